// Round 6
// baseline (269.018 us; speedup 1.0000x reference)
//
#include <hip/hip_runtime.h>
#include <hip/hip_bf16.h>

#define BB   64
#define CING 96
#define MIDC 192
#define HH   56
#define WWD  56
#define HWSZ (HH*WWD)
#define COUTC 96
#define BNEPS 1e-5f

typedef __attribute__((ext_vector_type(8))) short short8;
typedef __attribute__((ext_vector_type(8))) unsigned short ushort8v;
typedef __attribute__((ext_vector_type(4))) float float4v;
typedef unsigned short ushort_t;
typedef unsigned int uint_t;
typedef __attribute__((ext_vector_type(4))) uint_t uint4v;

// fast SiLU: v_rcp instead of IEEE div sequence (~10 VALU ops -> 1)
__device__ __forceinline__ float siluf(float v){
    return v * __builtin_amdgcn_rcpf(1.f + __expf(-v));
}
__device__ __forceinline__ ushort_t f2bs(float f){
    uint_t u = __float_as_uint(f);
    uint_t r = u + 0x7FFFu + ((u >> 16) & 1u);   // RNE; inputs are finite
    return (ushort_t)(r >> 16);
}
__device__ __forceinline__ float bs2f(ushort_t u){
    return __uint_as_float(((uint_t)u) << 16);
}
__device__ __forceinline__ uint_t pkbf(float a, float b){   // packed bf16 cvt (RNE)
    __hip_bfloat162 h = __float22bfloat162_rn(make_float2(a, b));
    union { __hip_bfloat162 h; uint_t u; } cv; cv.h = h; return cv.u;
}
__device__ __forceinline__ float bslo(uint_t x){ return __uint_as_float(x << 16); }
__device__ __forceinline__ float bshi(uint_t x){ return __uint_as_float(x & 0xFFFF0000u); }

// ---------------- k0: fold BNs, reorder+cast weights ---------------------------
__global__ __launch_bounds__(256) void k0_setup(
    const float* __restrict__ expand_w, const float* __restrict__ expand_bn,
    const float* __restrict__ dw_w, const float* __restrict__ dw_bn,
    const float* __restrict__ id_w, const float* __restrict__ id_bn,
    const float* __restrict__ merge_bn,
    const float* __restrict__ proj_w, const float* __restrict__ proj_bn,
    ushort_t* __restrict__ Aexp, float* __restrict__ ebias,
    float* __restrict__ w9f, float* __restrict__ cstf,
    ushort_t* __restrict__ Aproj, float* __restrict__ pscf, float* __restrict__ pshf)
{
    int i = blockIdx.x*256 + threadIdx.x;
    if (i < 4608) {                       // expand A: [m=192][k=96], BN-scale folded, shuffled
        int m = i/24, kq = (i%24)*4;
        int ic = (m&3)*48 + (m>>2);
        float sc0 = expand_bn[ic]*rsqrtf(expand_bn[3*MIDC+ic]+BNEPS);
        #pragma unroll
        for (int j=0;j<4;j++) Aexp[m*96+kq+j] = f2bs(expand_w[ic*96+kq+j]*sc0);
        if (kq==0) ebias[m] = expand_bn[MIDC+ic] - expand_bn[2*MIDC+ic]*sc0;
    } else if (i < 9216) {                // proj A: [m=96][k=192]
        int ii = i-4608; int m = ii/48, kq = (ii%48)*4;
        #pragma unroll
        for (int j=0;j<4;j++) Aproj[m*MIDC+kq+j] = f2bs(proj_w[m*MIDC+kq+j]);
        if (kq==0){
            float sc = proj_bn[m]*rsqrtf(proj_bn[3*COUTC+m]+BNEPS);
            pscf[m]=sc; pshf[m]=proj_bn[COUTC+m]-proj_bn[2*COUTC+m]*sc;
        }
    } else if (i < 9408) {                // dw folded taps
        int oc = i-9216;
        float sc1 = dw_bn[oc]    * rsqrtf(dw_bn[3*MIDC+oc]    + BNEPS);
        float sh1 = dw_bn[MIDC+oc]    - dw_bn[2*MIDC+oc]*sc1;
        float sc2 = id_bn[oc]    * rsqrtf(id_bn[3*MIDC+oc]    + BNEPS);
        float sh2 = id_bn[MIDC+oc]    - id_bn[2*MIDC+oc]*sc2;
        float sc3 = merge_bn[oc] * rsqrtf(merge_bn[3*MIDC+oc] + BNEPS);
        float sh3 = merge_bn[MIDC+oc] - merge_bn[2*MIDC+oc]*sc3;
        float A = sc3*sc1;
        #pragma unroll
        for (int j=0;j<9;j++) w9f[oc*9+j] = A*dw_w[oc*9+j];
        w9f[oc*9+4] += sc3*sc2*id_w[oc];
        cstf[oc] = sc3*(sh1+sh2) + sh3;
    }
}

// ---------------- k1: expand GEMM, staging loads hoisted for MLP ---------------
#define LDB1T 104
__global__ __launch_bounds__(256, 2) void k1_expand(
    const float* __restrict__ x,
    const ushort_t* __restrict__ Aexp,
    const float* __restrict__ ebias,
    ushort_t* __restrict__ EY)
{
    __shared__ __align__(16) ushort_t BsT[64*LDB1T];    // 13,312 B  [n][k]
    __shared__ float ebL[MIDC];
    const int t = threadIdx.x;
    const int p0 = blockIdx.x*64, b = blockIdx.y;

    if (t < MIDC) ebL[t] = ebias[t];
    {                                                   // stage B transposed: [n=64][k=96]
        const int n  = t & 63;
        const int kb = (t >> 6)*24;
        const float* xp0 = x + ((size_t)(b*CING + kb))*HWSZ + p0 + n;
        float xv[24];
        #pragma unroll
        for (int j = 0; j < 24; j++) xv[j] = xp0[(size_t)j*HWSZ];   // 24 loads in flight
        #pragma unroll
        for (int ii = 0; ii < 3; ii++) {
            uint4v w;
            #pragma unroll
            for (int j2 = 0; j2 < 4; j2++)
                w[j2] = pkbf(xv[ii*8+2*j2], xv[ii*8+2*j2+1]);       // v_cvt_pk_bf16_f32
            *(uint4v*)(&BsT[n*LDB1T + kb + ii*8]) = w;
        }
    }

    const int lane = t & 63, wv = t >> 6;
    const int l = lane & 15, q = lane >> 4;
    short8 afc[3], afn[3];                              // pipelined A (only 6 live)
    #pragma unroll
    for (int mi = 0; mi < 3; mi++)
        afc[mi] = *(const short8*)(Aexp + ((wv*3+mi)*16 + l)*96 + q*8);
    __syncthreads();

    float4v acc[3][4];
    #pragma unroll
    for (int mi=0;mi<3;mi++)
        #pragma unroll
        for (int nt=0;nt<4;nt++) acc[mi][nt] = (float4v){0.f,0.f,0.f,0.f};
    #pragma unroll
    for (int ks = 0; ks < 3; ks++) {
        if (ks < 2) {
            #pragma unroll
            for (int mi = 0; mi < 3; mi++)
                afn[mi] = *(const short8*)(Aexp + ((wv*3+mi)*16 + l)*96 + (ks+1)*32 + q*8);
        }
        const int k0 = ks*32;
        short8 bf[4];
        #pragma unroll
        for (int nt = 0; nt < 4; nt++)
            bf[nt] = *(const short8*)(&BsT[(nt*16 + l)*LDB1T + k0 + q*8]);
        #pragma unroll
        for (int mi = 0; mi < 3; mi++)
            #pragma unroll
            for (int nt = 0; nt < 4; nt++)
                acc[mi][nt] = __builtin_amdgcn_mfma_f32_16x16x32_bf16(afc[mi], bf[nt], acc[mi][nt], 0,0,0);
        if (ks < 2) {
            #pragma unroll
            for (int mi = 0; mi < 3; mi++) afc[mi] = afn[mi];
        }
    }
    #pragma unroll
    for (int mi = 0; mi < 3; mi++) {
        #pragma unroll
        for (int r = 0; r < 4; r++) {
            int m = (wv*3+mi)*16 + q*4 + r;
            float eb = ebL[m];
            size_t rowb = (size_t)(b*MIDC + m)*HWSZ + p0 + l;
            #pragma unroll
            for (int nt = 0; nt < 4; nt++)
                EY[rowb + nt*16] = f2bs(siluf(acc[mi][nt][r] + eb));
        }
    }
}

// ---------------- k2: shifted dw3x3 + SiLU, 8-col uint4, 2 ch per lane-group ---
// 16-lane group: lanes 0-6 = channel A cols 8*li, lanes 8-14 = channel B.
// Halves shuffle/load/store/loop-overhead per element vs the 4-col version.
template<int DY, int DX>
__device__ __forceinline__ float dw_plane8(
    ushort_t* __restrict__ plane, const float* __restrict__ w9, float cst,
    int li8, int h, bool act)
{
    const int cc = (li8 < 7) ? li8 : 6;                 // clamp idle lane in-bounds
    // conflict rows (other half overwrites them after the barrier): preload
    uint4 pA = make_uint4(0,0,0,0), pB = make_uint4(0,0,0,0);
    int rA = -100, rB = -100;
    if (h == 0) { if (DY==1){ rA=28; rB=29; } else if (DY==0){ rA=28; } }
    else        { if (DY==-1){ rA=26; rB=27; } else if (DY==0){ rA=27; } }
    const ushort_t* pl = plane + cc*8;
    if (rA >= 0) pA = *(const uint4*)(pl + rA*WWD);
    if (rB >= 0) pB = *(const uint4*)(pl + rB*WWD);
    __syncthreads();

    const int ys = h ? 27 : -1;
    const int so = h ? 29 : 1;

    auto loadrow = [&](int y) -> uint4 {
        int yy = y + DY;
        uint4 u = make_uint4(0,0,0,0);
        if (((unsigned)y < (unsigned)HH) && ((unsigned)yy < (unsigned)HH)) {
            if (yy == rA)      u = pA;
            else if (yy == rB) u = pB;
            else               u = *(const uint4*)(pl + yy*WWD);
        }
        return u;
    };

    float p0[8] = {0,0,0,0,0,0,0,0}, p1[8] = {0,0,0,0,0,0,0,0};
    float partial = 0.f;
    uint4 u = loadrow(ys);
    for (int y = ys; y <= ys + 29; ++y) {
        uint4 un = loadrow(y + 1);              // prefetch BEFORE this iter's store
        uint_t lhi = __shfl_up(u.w, 1);         // cols c0-2,c0-1
        uint_t rlo = __shfl_down(u.x, 1);       // cols c0+8,c0+9
        if (li8 == 0) lhi = 0u;
        if (li8 == 6) rlo = 0u;
        float s[12];
        s[0]=bslo(lhi);  s[1]=bshi(lhi);
        s[2]=bslo(u.x);  s[3]=bshi(u.x);
        s[4]=bslo(u.y);  s[5]=bshi(u.y);
        s[6]=bslo(u.z);  s[7]=bshi(u.z);
        s[8]=bslo(u.w);  s[9]=bshi(u.w);
        s[10]=bslo(rlo); s[11]=bshi(rlo);
        if (li8 == 0) s[DX+1]  = 0.f;           // shift/conv zero at left edge
        if (li8 == 6) s[DX+10] = 0.f;           // shift/conv zero at right edge
        float o[8];
        #pragma unroll
        for (int j = 0; j < 8; j++) {
            float t0 = s[j+DX+1], t1 = s[j+DX+2], t2 = s[j+DX+3];
            // cst seeded into the p0 chain (reaches each output exactly once)
            o[j]  = fmaf(w9[6],t0, fmaf(w9[7],t1, fmaf(w9[8],t2, p1[j])));
            p1[j] = fmaf(w9[3],t0, fmaf(w9[4],t1, fmaf(w9[5],t2, p0[j])));
            p0[j] = fmaf(w9[0],t0, fmaf(w9[1],t1, fmaf(w9[2],t2, cst)));
        }
        if (y >= so && act) {
            float y0=siluf(o[0]), y1=siluf(o[1]), y2=siluf(o[2]), y3=siluf(o[3]);
            float y4=siluf(o[4]), y5=siluf(o[5]), y6=siluf(o[6]), y7=siluf(o[7]);
            uint4 w4; w4.x=pkbf(y0,y1); w4.y=pkbf(y2,y3); w4.z=pkbf(y4,y5); w4.w=pkbf(y6,y7);
            *(uint4*)(plane + (size_t)(y-1)*WWD + li8*8) = w4;
            partial += ((y0+y1)+(y2+y3)) + ((y4+y5)+(y6+y7));
        }
        u = un;
    }
    #pragma unroll
    for (int off = 1; off < 8; off <<= 1) partial += __shfl_xor(partial, off);
    return partial;
}

__global__ __launch_bounds__(128) void k2_dw(
    ushort_t* __restrict__ EY,
    const float* __restrict__ w9f,
    const float* __restrict__ cstf,
    float* __restrict__ sums)
{
    __shared__ float wred[16];
    const int t = threadIdx.x;
    const int lane = t & 63, h = t >> 6;
    const int lg = lane >> 4;                 // 0..3 lane-group
    const int li = lane & 15;
    const int li8 = li & 7;
    const int hi = li >> 3;                   // channel within group (0/1)
    const int gi = blockIdx.x >> 2, r = blockIdx.x & 3;   // r = shift group (uniform)
    const int b = blockIdx.y;
    const int oc = gi*32 + r + (lg*2 + hi)*4;
    ushort_t* plane = EY + (size_t)(b*MIDC + oc)*HWSZ;
    float w9[9];
    #pragma unroll
    for (int j = 0; j < 9; j++) w9[j] = w9f[oc*9+j];
    const float cst = cstf[oc];
    const bool act = (li8 < 7);
    float ps;
    if      (r == 0) ps = dw_plane8<-1, 0>(plane, w9, cst, li8, h, act);
    else if (r == 1) ps = dw_plane8< 0,-1>(plane, w9, cst, li8, h, act);
    else if (r == 2) ps = dw_plane8< 1, 0>(plane, w9, cst, li8, h, act);
    else             ps = dw_plane8< 0, 1>(plane, w9, cst, li8, h, act);
    if (li8 == 0) wred[h*8 + lg*2 + hi] = ps;
    __syncthreads();
    if (t < 8) sums[b*MIDC + gi*32 + r + t*4] = wred[t] + wred[8 + t];
}

// ---------------- k4: proj GEMM, SE inline, staged+epilogue loads hoisted ------
#define LDB4T 200
__global__ __launch_bounds__(256, 2) void k4_proj(
    const ushort_t* __restrict__ EY,
    const float* __restrict__ sums,
    const float* __restrict__ se_red_w, const float* __restrict__ se_red_b,
    const float* __restrict__ se_exp_w, const float* __restrict__ se_exp_b,
    const ushort_t* __restrict__ Aproj,
    const float* __restrict__ pscf, const float* __restrict__ pshf,
    const float* __restrict__ x,
    float* __restrict__ out)
{
    __shared__ __align__(16) ushort_t BsT[64*LDB4T];     // 25,600 B  [n][k]
    __shared__ float pscL[COUTC], pshL[COUTC];
    __shared__ float meanL[MIDC], redL[24], sewL[MIDC];
    const int t = threadIdx.x;
    const int p0 = blockIdx.x*64, b = blockIdx.y;
    if (t < COUTC) { pscL[t] = pscf[t]; pshL[t] = pshf[t]; }

    // --- inline SE (was k3): sums -> gates, redundantly per block (L2-hot) ---
    if (t < MIDC) meanL[t] = sums[b*MIDC + t] * (1.f/(float)HWSZ);
    __syncthreads();
    if (t < 24) {
        int g = t >> 1;
        float a = se_red_b[t];
        #pragma unroll
        for (int i = 0; i < 16; i++) a += meanL[g*16+i] * se_red_w[t*16+i];
        redL[t] = fmaxf(a, 0.f);
    }
    __syncthreads();
    if (t < MIDC) {
        int g = t >> 4;
        float a = se_exp_b[t] + redL[g*2]*se_exp_w[t*2] + redL[g*2+1]*se_exp_w[t*2+1];
        sewL[t] = __builtin_amdgcn_rcpf(1.f + __expf(-a));
    }
    __syncthreads();

    {                                                   // stage B transposed, SE folded
        const int n  = t & 63;
        const int kb = (t >> 6)*48;
        const ushort_t* ep0 = EY + ((size_t)(b*MIDC + kb))*HWSZ + p0 + n;
        ushort_t ev[48];
        #pragma unroll
        for (int j = 0; j < 48; j++) ev[j] = ep0[(size_t)j*HWSZ];   // 48 loads in flight
        #pragma unroll
        for (int ii = 0; ii < 6; ii++) {
            uint4v w;
            #pragma unroll
            for (int j2 = 0; j2 < 4; j2++) {
                int k8 = ii*8 + 2*j2;
                float a = bs2f(ev[k8  ]) * sewL[kb+k8  ];
                float c = bs2f(ev[k8+1]) * sewL[kb+k8+1];
                w[j2] = pkbf(a, c);                     // v_cvt_pk_bf16_f32
            }
            *(uint4v*)(&BsT[n*LDB4T + kb + ii*8]) = w;
        }
    }

    const int lane = t & 63, wv = t >> 6;
    const int l = lane & 15, q = lane >> 4;
    const int mh = wv >> 1, nh = wv & 1;
    short8 afc[3], afn[3];                              // pipelined A (only 6 live)
    #pragma unroll
    for (int mi = 0; mi < 3; mi++)
        afc[mi] = *(const short8*)(Aproj + ((mh*3+mi)*16 + l)*MIDC + q*8);
    __syncthreads();

    // prefetch ALL residual x values now; they land under the MFMA phase
    float xpre[24];
    #pragma unroll
    for (int mi = 0; mi < 3; mi++) {
        #pragma unroll
        for (int r = 0; r < 4; r++) {
            size_t rowb = (size_t)(b*COUTC + (mh*3+mi)*16 + q*4 + r)*HWSZ + p0 + nh*32 + l;
            xpre[(mi*4+r)*2  ] = x[rowb];
            xpre[(mi*4+r)*2+1] = x[rowb + 16];
        }
    }

    float4v acc[3][2];
    #pragma unroll
    for (int mi=0;mi<3;mi++)
        #pragma unroll
        for (int nt=0;nt<2;nt++) acc[mi][nt] = (float4v){0.f,0.f,0.f,0.f};
    #pragma unroll
    for (int ks = 0; ks < 6; ks++) {
        if (ks < 5) {
            #pragma unroll
            for (int mi = 0; mi < 3; mi++)
                afn[mi] = *(const short8*)(Aproj + ((mh*3+mi)*16 + l)*MIDC + (ks+1)*32 + q*8);
        }
        const int k0 = ks*32;
        short8 bf[2];
        #pragma unroll
        for (int nt = 0; nt < 2; nt++)
            bf[nt] = *(const short8*)(&BsT[(nh*32 + nt*16 + l)*LDB4T + k0 + q*8]);
        #pragma unroll
        for (int mi = 0; mi < 3; mi++)
            #pragma unroll
            for (int nt = 0; nt < 2; nt++)
                acc[mi][nt] = __builtin_amdgcn_mfma_f32_16x16x32_bf16(afc[mi], bf[nt], acc[mi][nt], 0,0,0);
        if (ks < 5) {
            #pragma unroll
            for (int mi = 0; mi < 3; mi++) afc[mi] = afn[mi];
        }
    }
    #pragma unroll
    for (int mi = 0; mi < 3; mi++) {
        #pragma unroll
        for (int r = 0; r < 4; r++) {
            int m = (mh*3+mi)*16 + q*4 + r;
            float sc = pscL[m], sh = pshL[m];
            size_t rowb = (size_t)(b*COUTC + m)*HWSZ + p0 + nh*32 + l;
            #pragma unroll
            for (int nt = 0; nt < 2; nt++) {
                size_t idx = rowb + nt*16;
                float v = acc[mi][nt][r]*sc + sh + xpre[(mi*4+r)*2+nt];
                out[idx] = siluf(v);
            }
        }
    }
}

extern "C" void kernel_launch(void* const* d_in, const int* in_sizes, int n_in,
                              void* d_out, int out_size, void* d_ws, size_t ws_size,
                              hipStream_t stream)
{
    const float* x         = (const float*)d_in[0];
    const float* expand_w  = (const float*)d_in[1];
    const float* expand_bn = (const float*)d_in[2];
    const float* dw_w      = (const float*)d_in[3];
    const float* dw_bn     = (const float*)d_in[4];
    const float* id_w      = (const float*)d_in[5];
    const float* id_bn     = (const float*)d_in[6];
    const float* merge_bn  = (const float*)d_in[7];
    const float* se_red_w  = (const float*)d_in[8];
    const float* se_red_b  = (const float*)d_in[9];
    const float* se_exp_w  = (const float*)d_in[10];
    const float* se_exp_b  = (const float*)d_in[11];
    const float* proj_w    = (const float*)d_in[12];
    const float* proj_bn   = (const float*)d_in[13];

    char* base = (char*)d_ws;
    size_t off = 0;
    ushort_t* EY   = (ushort_t*)(base + off); off += (size_t)BB*MIDC*HWSZ*2;  // 77,070,336
    float* sums    = (float*)(base + off);    off += BB*MIDC*4;
    ushort_t* Aexp = (ushort_t*)(base + off); off += MIDC*CING*2;
    ushort_t* Aproj= (ushort_t*)(base + off); off += COUTC*MIDC*2;
    float* ebias   = (float*)(base + off);    off += MIDC*4;
    float* w9f     = (float*)(base + off);    off += MIDC*9*4;
    float* cstf    = (float*)(base + off);    off += MIDC*4;
    float* pscf    = (float*)(base + off);    off += COUTC*4;
    float* pshf    = (float*)(base + off);    off += COUTC*4;

    k0_setup<<<dim3(37), dim3(256), 0, stream>>>(
        expand_w, expand_bn, dw_w, dw_bn, id_w, id_bn, merge_bn, proj_w, proj_bn,
        Aexp, ebias, w9f, cstf, Aproj, pscf, pshf);
    k1_expand<<<dim3(HWSZ/64, BB), dim3(256), 0, stream>>>(x, Aexp, ebias, EY);
    k2_dw<<<dim3(24, BB), dim3(128), 0, stream>>>(EY, w9f, cstf, sums);
    k4_proj<<<dim3(HWSZ/64, BB), dim3(256), 0, stream>>>(
        EY, sums, se_red_w, se_red_b, se_exp_w, se_exp_b,
        Aproj, pscf, pshf, x, (float*)d_out);
}

// Round 7
// 262.690 us; speedup vs baseline: 1.0241x; 1.0241x over previous
//
#include <hip/hip_runtime.h>
#include <hip/hip_bf16.h>

#define BB   64
#define CING 96
#define MIDC 192
#define HH   56
#define WWD  56
#define HWSZ (HH*WWD)
#define COUTC 96
#define BNEPS 1e-5f

typedef __attribute__((ext_vector_type(8))) short short8;
typedef __attribute__((ext_vector_type(8))) unsigned short ushort8v;
typedef __attribute__((ext_vector_type(4))) float float4v;
typedef unsigned short ushort_t;
typedef unsigned int uint_t;
typedef __attribute__((ext_vector_type(4))) uint_t uint4v;

// fast SiLU: v_rcp instead of IEEE div sequence (~10 VALU ops -> 1)
__device__ __forceinline__ float siluf(float v){
    return v * __builtin_amdgcn_rcpf(1.f + __expf(-v));
}
__device__ __forceinline__ ushort_t f2bs(float f){
    uint_t u = __float_as_uint(f);
    uint_t r = u + 0x7FFFu + ((u >> 16) & 1u);   // RNE; inputs are finite
    return (ushort_t)(r >> 16);
}
__device__ __forceinline__ float bs2f(ushort_t u){
    return __uint_as_float(((uint_t)u) << 16);
}
__device__ __forceinline__ uint_t pkbf(float a, float b){   // packed bf16 cvt (RNE)
    __hip_bfloat162 h = __float22bfloat162_rn(make_float2(a, b));
    union { __hip_bfloat162 h; uint_t u; } cv; cv.h = h; return cv.u;
}
__device__ __forceinline__ float bslo(uint_t x){ return __uint_as_float(x << 16); }
__device__ __forceinline__ float bshi(uint_t x){ return __uint_as_float(x & 0xFFFF0000u); }

// ---------------- k0: fold BNs, reorder+cast weights ---------------------------
__global__ __launch_bounds__(256) void k0_setup(
    const float* __restrict__ expand_w, const float* __restrict__ expand_bn,
    const float* __restrict__ dw_w, const float* __restrict__ dw_bn,
    const float* __restrict__ id_w, const float* __restrict__ id_bn,
    const float* __restrict__ merge_bn,
    const float* __restrict__ proj_w, const float* __restrict__ proj_bn,
    ushort_t* __restrict__ Aexp, float* __restrict__ ebias,
    float* __restrict__ w9f, float* __restrict__ cstf,
    ushort_t* __restrict__ Aproj, float* __restrict__ pscf, float* __restrict__ pshf)
{
    int i = blockIdx.x*256 + threadIdx.x;
    if (i < 4608) {                       // expand A: [m=192][k=96], BN-scale folded, shuffled
        int m = i/24, kq = (i%24)*4;
        int ic = (m&3)*48 + (m>>2);
        float sc0 = expand_bn[ic]*rsqrtf(expand_bn[3*MIDC+ic]+BNEPS);
        #pragma unroll
        for (int j=0;j<4;j++) Aexp[m*96+kq+j] = f2bs(expand_w[ic*96+kq+j]*sc0);
        if (kq==0) ebias[m] = expand_bn[MIDC+ic] - expand_bn[2*MIDC+ic]*sc0;
    } else if (i < 9216) {                // proj A: [m=96][k=192]
        int ii = i-4608; int m = ii/48, kq = (ii%48)*4;
        #pragma unroll
        for (int j=0;j<4;j++) Aproj[m*MIDC+kq+j] = f2bs(proj_w[m*MIDC+kq+j]);
        if (kq==0){
            float sc = proj_bn[m]*rsqrtf(proj_bn[3*COUTC+m]+BNEPS);
            pscf[m]=sc; pshf[m]=proj_bn[COUTC+m]-proj_bn[2*COUTC+m]*sc;
        }
    } else if (i < 9408) {                // dw folded taps
        int oc = i-9216;
        float sc1 = dw_bn[oc]    * rsqrtf(dw_bn[3*MIDC+oc]    + BNEPS);
        float sh1 = dw_bn[MIDC+oc]    - dw_bn[2*MIDC+oc]*sc1;
        float sc2 = id_bn[oc]    * rsqrtf(id_bn[3*MIDC+oc]    + BNEPS);
        float sh2 = id_bn[MIDC+oc]    - id_bn[2*MIDC+oc]*sc2;
        float sc3 = merge_bn[oc] * rsqrtf(merge_bn[3*MIDC+oc] + BNEPS);
        float sh3 = merge_bn[MIDC+oc] - merge_bn[2*MIDC+oc]*sc3;
        float A = sc3*sc1;
        #pragma unroll
        for (int j=0;j<9;j++) w9f[oc*9+j] = A*dw_w[oc*9+j];
        w9f[oc*9+4] += sc3*sc2*id_w[oc];
        cstf[oc] = sc3*(sh1+sh2) + sh3;
    }
}

// ---------------- k1: expand GEMM, WIDE staging (6 x float4 per thread) --------
// Thread maps to 4 consecutive pixels x 6 channels: 6 x 16B loads (vs 24 scalar)
// -> single memory-latency exposure per wave instead of serial round-trips.
#define LDB1T 104
__global__ __launch_bounds__(256, 2) void k1_expand(
    const float* __restrict__ x,
    const ushort_t* __restrict__ Aexp,
    const float* __restrict__ ebias,
    ushort_t* __restrict__ EY)
{
    __shared__ __align__(16) ushort_t BsT[64*LDB1T];    // 13,312 B  [n][k]
    __shared__ float ebL[MIDC];
    const int t = threadIdx.x;
    const int p0 = blockIdx.x*64, b = blockIdx.y;

    if (t < MIDC) ebL[t] = ebias[t];
    {                                                   // stage B transposed: [n=64][k=96]
        const int pq = t & 15;                          // pixel quad
        const int cb = (t >> 4) * 6;                    // 6 channels
        const float* xp0 = x + ((size_t)(b*CING + cb))*HWSZ + p0 + pq*4;
        float4v xv[6];
        #pragma unroll
        for (int j = 0; j < 6; j++)
            xv[j] = *(const float4v*)(xp0 + (size_t)j*HWSZ);   // 6x16B in flight
        #pragma unroll
        for (int px = 0; px < 4; px++) {
            const int n = pq*4 + px;
            uint_t w0 = pkbf(xv[0][px], xv[1][px]);
            uint_t w1 = pkbf(xv[2][px], xv[3][px]);
            uint_t w2 = pkbf(xv[4][px], xv[5][px]);
            uint_t* dst = (uint_t*)(&BsT[n*LDB1T + cb]);
            dst[0] = w0; dst[1] = w1; dst[2] = w2;
        }
    }

    const int lane = t & 63, wv = t >> 6;
    const int l = lane & 15, q = lane >> 4;
    short8 afc[3], afn[3];                              // pipelined A (only 6 live)
    #pragma unroll
    for (int mi = 0; mi < 3; mi++)
        afc[mi] = *(const short8*)(Aexp + ((wv*3+mi)*16 + l)*96 + q*8);
    __syncthreads();

    float4v acc[3][4];
    #pragma unroll
    for (int mi=0;mi<3;mi++)
        #pragma unroll
        for (int nt=0;nt<4;nt++) acc[mi][nt] = (float4v){0.f,0.f,0.f,0.f};
    #pragma unroll
    for (int ks = 0; ks < 3; ks++) {
        if (ks < 2) {
            #pragma unroll
            for (int mi = 0; mi < 3; mi++)
                afn[mi] = *(const short8*)(Aexp + ((wv*3+mi)*16 + l)*96 + (ks+1)*32 + q*8);
        }
        const int k0 = ks*32;
        short8 bf[4];
        #pragma unroll
        for (int nt = 0; nt < 4; nt++)
            bf[nt] = *(const short8*)(&BsT[(nt*16 + l)*LDB1T + k0 + q*8]);
        #pragma unroll
        for (int mi = 0; mi < 3; mi++)
            #pragma unroll
            for (int nt = 0; nt < 4; nt++)
                acc[mi][nt] = __builtin_amdgcn_mfma_f32_16x16x32_bf16(afc[mi], bf[nt], acc[mi][nt], 0,0,0);
        if (ks < 2) {
            #pragma unroll
            for (int mi = 0; mi < 3; mi++) afc[mi] = afn[mi];
        }
    }
    #pragma unroll
    for (int mi = 0; mi < 3; mi++) {
        #pragma unroll
        for (int r = 0; r < 4; r++) {
            int m = (wv*3+mi)*16 + q*4 + r;
            float eb = ebL[m];
            size_t rowb = (size_t)(b*MIDC + m)*HWSZ + p0 + l;
            #pragma unroll
            for (int nt = 0; nt < 4; nt++)
                EY[rowb + nt*16] = f2bs(siluf(acc[mi][nt][r] + eb));
        }
    }
}

// ---------------- k2: shifted dw3x3 + SiLU, 8-col uint4, 2 ch per lane-group ---
template<int DY, int DX>
__device__ __forceinline__ float dw_plane8(
    ushort_t* __restrict__ plane, const float* __restrict__ w9, float cst,
    int li8, int h, bool act)
{
    const int cc = (li8 < 7) ? li8 : 6;                 // clamp idle lane in-bounds
    // conflict rows (other half overwrites them after the barrier): preload
    uint4 pA = make_uint4(0,0,0,0), pB = make_uint4(0,0,0,0);
    int rA = -100, rB = -100;
    if (h == 0) { if (DY==1){ rA=28; rB=29; } else if (DY==0){ rA=28; } }
    else        { if (DY==-1){ rA=26; rB=27; } else if (DY==0){ rA=27; } }
    const ushort_t* pl = plane + cc*8;
    if (rA >= 0) pA = *(const uint4*)(pl + rA*WWD);
    if (rB >= 0) pB = *(const uint4*)(pl + rB*WWD);
    __syncthreads();

    const int ys = h ? 27 : -1;
    const int so = h ? 29 : 1;

    auto loadrow = [&](int y) -> uint4 {
        int yy = y + DY;
        uint4 u = make_uint4(0,0,0,0);
        if (((unsigned)y < (unsigned)HH) && ((unsigned)yy < (unsigned)HH)) {
            if (yy == rA)      u = pA;
            else if (yy == rB) u = pB;
            else               u = *(const uint4*)(pl + yy*WWD);
        }
        return u;
    };

    float p0[8] = {0,0,0,0,0,0,0,0}, p1[8] = {0,0,0,0,0,0,0,0};
    float partial = 0.f;
    uint4 u = loadrow(ys);
    for (int y = ys; y <= ys + 29; ++y) {
        uint4 un = loadrow(y + 1);              // prefetch BEFORE this iter's store
        uint_t lhi = __shfl_up(u.w, 1);         // cols c0-2,c0-1
        uint_t rlo = __shfl_down(u.x, 1);       // cols c0+8,c0+9
        if (li8 == 0) lhi = 0u;
        if (li8 == 6) rlo = 0u;
        float s[12];
        s[0]=bslo(lhi);  s[1]=bshi(lhi);
        s[2]=bslo(u.x);  s[3]=bshi(u.x);
        s[4]=bslo(u.y);  s[5]=bshi(u.y);
        s[6]=bslo(u.z);  s[7]=bshi(u.z);
        s[8]=bslo(u.w);  s[9]=bshi(u.w);
        s[10]=bslo(rlo); s[11]=bshi(rlo);
        if (li8 == 0) s[DX+1]  = 0.f;           // shift/conv zero at left edge
        if (li8 == 6) s[DX+10] = 0.f;           // shift/conv zero at right edge
        float o[8];
        #pragma unroll
        for (int j = 0; j < 8; j++) {
            float t0 = s[j+DX+1], t1 = s[j+DX+2], t2 = s[j+DX+3];
            // cst seeded into the p0 chain (reaches each output exactly once)
            o[j]  = fmaf(w9[6],t0, fmaf(w9[7],t1, fmaf(w9[8],t2, p1[j])));
            p1[j] = fmaf(w9[3],t0, fmaf(w9[4],t1, fmaf(w9[5],t2, p0[j])));
            p0[j] = fmaf(w9[0],t0, fmaf(w9[1],t1, fmaf(w9[2],t2, cst)));
        }
        if (y >= so && act) {
            float y0=siluf(o[0]), y1=siluf(o[1]), y2=siluf(o[2]), y3=siluf(o[3]);
            float y4=siluf(o[4]), y5=siluf(o[5]), y6=siluf(o[6]), y7=siluf(o[7]);
            uint4 w4; w4.x=pkbf(y0,y1); w4.y=pkbf(y2,y3); w4.z=pkbf(y4,y5); w4.w=pkbf(y6,y7);
            *(uint4*)(plane + (size_t)(y-1)*WWD + li8*8) = w4;
            partial += ((y0+y1)+(y2+y3)) + ((y4+y5)+(y6+y7));
        }
        u = un;
    }
    #pragma unroll
    for (int off = 1; off < 8; off <<= 1) partial += __shfl_xor(partial, off);
    return partial;
}

__global__ __launch_bounds__(128) void k2_dw(
    ushort_t* __restrict__ EY,
    const float* __restrict__ w9f,
    const float* __restrict__ cstf,
    float* __restrict__ sums)
{
    __shared__ float wred[16];
    const int t = threadIdx.x;
    const int lane = t & 63, h = t >> 6;
    const int lg = lane >> 4;                 // 0..3 lane-group
    const int li = lane & 15;
    const int li8 = li & 7;
    const int hi = li >> 3;                   // channel within group (0/1)
    const int gi = blockIdx.x >> 2, r = blockIdx.x & 3;   // r = shift group (uniform)
    const int b = blockIdx.y;
    const int oc = gi*32 + r + (lg*2 + hi)*4;
    ushort_t* plane = EY + (size_t)(b*MIDC + oc)*HWSZ;
    float w9[9];
    #pragma unroll
    for (int j = 0; j < 9; j++) w9[j] = w9f[oc*9+j];
    const float cst = cstf[oc];
    const bool act = (li8 < 7);
    float ps;
    if      (r == 0) ps = dw_plane8<-1, 0>(plane, w9, cst, li8, h, act);
    else if (r == 1) ps = dw_plane8< 0,-1>(plane, w9, cst, li8, h, act);
    else if (r == 2) ps = dw_plane8< 1, 0>(plane, w9, cst, li8, h, act);
    else             ps = dw_plane8< 0, 1>(plane, w9, cst, li8, h, act);
    if (li8 == 0) wred[h*8 + lg*2 + hi] = ps;
    __syncthreads();
    if (t < 8) sums[b*MIDC + gi*32 + r + t*4] = wred[t] + wred[8 + t];
}

// ---------------- k4: proj GEMM, SE inline, WIDE staging (6 x 16B per thread) --
#define LDB4T 200
__global__ __launch_bounds__(256, 2) void k4_proj(
    const ushort_t* __restrict__ EY,
    const float* __restrict__ sums,
    const float* __restrict__ se_red_w, const float* __restrict__ se_red_b,
    const float* __restrict__ se_exp_w, const float* __restrict__ se_exp_b,
    const ushort_t* __restrict__ Aproj,
    const float* __restrict__ pscf, const float* __restrict__ pshf,
    const float* __restrict__ x,
    float* __restrict__ out)
{
    __shared__ __align__(16) ushort_t BsT[64*LDB4T];     // 25,600 B  [n][k]
    __shared__ float pscL[COUTC], pshL[COUTC];
    __shared__ float meanL[MIDC], redL[24], sewL[MIDC];
    const int t = threadIdx.x;
    const int p0 = blockIdx.x*64, b = blockIdx.y;
    if (t < COUTC) { pscL[t] = pscf[t]; pshL[t] = pshf[t]; }

    // --- inline SE (was k3): sums -> gates, redundantly per block (L2-hot) ---
    if (t < MIDC) meanL[t] = sums[b*MIDC + t] * (1.f/(float)HWSZ);
    __syncthreads();
    if (t < 24) {
        int g = t >> 1;
        float a = se_red_b[t];
        #pragma unroll
        for (int i = 0; i < 16; i++) a += meanL[g*16+i] * se_red_w[t*16+i];
        redL[t] = fmaxf(a, 0.f);
    }
    __syncthreads();
    if (t < MIDC) {
        int g = t >> 4;
        float a = se_exp_b[t] + redL[g*2]*se_exp_w[t*2] + redL[g*2+1]*se_exp_w[t*2+1];
        sewL[t] = __builtin_amdgcn_rcpf(1.f + __expf(-a));
    }
    __syncthreads();

    {                                                   // stage B transposed, SE folded
        const int po = t & 7;                           // pixel oct
        const int cb = (t >> 3) * 6;                    // 6 channels
        const ushort_t* ep0 = EY + ((size_t)(b*MIDC + cb))*HWSZ + p0 + po*8;
        ushort8v ev[6];
        #pragma unroll
        for (int j = 0; j < 6; j++)
            ev[j] = *(const ushort8v*)(ep0 + (size_t)j*HWSZ);   // 6x16B in flight
        float sw[6];
        #pragma unroll
        for (int j = 0; j < 6; j++) sw[j] = sewL[cb + j];
        #pragma unroll
        for (int i = 0; i < 8; i++) {
            const int n = po*8 + i;
            uint_t w0 = pkbf(bs2f(ev[0][i])*sw[0], bs2f(ev[1][i])*sw[1]);
            uint_t w1 = pkbf(bs2f(ev[2][i])*sw[2], bs2f(ev[3][i])*sw[3]);
            uint_t w2 = pkbf(bs2f(ev[4][i])*sw[4], bs2f(ev[5][i])*sw[5]);
            uint_t* dst = (uint_t*)(&BsT[n*LDB4T + cb]);
            dst[0] = w0; dst[1] = w1; dst[2] = w2;
        }
    }

    const int lane = t & 63, wv = t >> 6;
    const int l = lane & 15, q = lane >> 4;
    const int mh = wv >> 1, nh = wv & 1;
    short8 afc[3], afn[3];                              // pipelined A (only 6 live)
    #pragma unroll
    for (int mi = 0; mi < 3; mi++)
        afc[mi] = *(const short8*)(Aproj + ((mh*3+mi)*16 + l)*MIDC + q*8);
    __syncthreads();

    // prefetch ALL residual x values now; they land under the MFMA phase
    float xpre[24];
    #pragma unroll
    for (int mi = 0; mi < 3; mi++) {
        #pragma unroll
        for (int r = 0; r < 4; r++) {
            size_t rowb = (size_t)(b*COUTC + (mh*3+mi)*16 + q*4 + r)*HWSZ + p0 + nh*32 + l;
            xpre[(mi*4+r)*2  ] = x[rowb];
            xpre[(mi*4+r)*2+1] = x[rowb + 16];
        }
    }

    float4v acc[3][2];
    #pragma unroll
    for (int mi=0;mi<3;mi++)
        #pragma unroll
        for (int nt=0;nt<2;nt++) acc[mi][nt] = (float4v){0.f,0.f,0.f,0.f};
    #pragma unroll
    for (int ks = 0; ks < 6; ks++) {
        if (ks < 5) {
            #pragma unroll
            for (int mi = 0; mi < 3; mi++)
                afn[mi] = *(const short8*)(Aproj + ((mh*3+mi)*16 + l)*MIDC + (ks+1)*32 + q*8);
        }
        const int k0 = ks*32;
        short8 bf[2];
        #pragma unroll
        for (int nt = 0; nt < 2; nt++)
            bf[nt] = *(const short8*)(&BsT[(nh*32 + nt*16 + l)*LDB4T + k0 + q*8]);
        #pragma unroll
        for (int mi = 0; mi < 3; mi++)
            #pragma unroll
            for (int nt = 0; nt < 2; nt++)
                acc[mi][nt] = __builtin_amdgcn_mfma_f32_16x16x32_bf16(afc[mi], bf[nt], acc[mi][nt], 0,0,0);
        if (ks < 5) {
            #pragma unroll
            for (int mi = 0; mi < 3; mi++) afc[mi] = afn[mi];
        }
    }
    #pragma unroll
    for (int mi = 0; mi < 3; mi++) {
        #pragma unroll
        for (int r = 0; r < 4; r++) {
            int m = (mh*3+mi)*16 + q*4 + r;
            float sc = pscL[m], sh = pshL[m];
            size_t rowb = (size_t)(b*COUTC + m)*HWSZ + p0 + nh*32 + l;
            #pragma unroll
            for (int nt = 0; nt < 2; nt++) {
                size_t idx = rowb + nt*16;
                float v = acc[mi][nt][r]*sc + sh + xpre[(mi*4+r)*2+nt];
                out[idx] = siluf(v);
            }
        }
    }
}

extern "C" void kernel_launch(void* const* d_in, const int* in_sizes, int n_in,
                              void* d_out, int out_size, void* d_ws, size_t ws_size,
                              hipStream_t stream)
{
    const float* x         = (const float*)d_in[0];
    const float* expand_w  = (const float*)d_in[1];
    const float* expand_bn = (const float*)d_in[2];
    const float* dw_w      = (const float*)d_in[3];
    const float* dw_bn     = (const float*)d_in[4];
    const float* id_w      = (const float*)d_in[5];
    const float* id_bn     = (const float*)d_in[6];
    const float* merge_bn  = (const float*)d_in[7];
    const float* se_red_w  = (const float*)d_in[8];
    const float* se_red_b  = (const float*)d_in[9];
    const float* se_exp_w  = (const float*)d_in[10];
    const float* se_exp_b  = (const float*)d_in[11];
    const float* proj_w    = (const float*)d_in[12];
    const float* proj_bn   = (const float*)d_in[13];

    char* base = (char*)d_ws;
    size_t off = 0;
    ushort_t* EY   = (ushort_t*)(base + off); off += (size_t)BB*MIDC*HWSZ*2;  // 77,070,336
    float* sums    = (float*)(base + off);    off += BB*MIDC*4;
    ushort_t* Aexp = (ushort_t*)(base + off); off += MIDC*CING*2;
    ushort_t* Aproj= (ushort_t*)(base + off); off += COUTC*MIDC*2;
    float* ebias   = (float*)(base + off);    off += MIDC*4;
    float* w9f     = (float*)(base + off);    off += MIDC*9*4;
    float* cstf    = (float*)(base + off);    off += MIDC*4;
    float* pscf    = (float*)(base + off);    off += COUTC*4;
    float* pshf    = (float*)(base + off);    off += COUTC*4;

    k0_setup<<<dim3(37), dim3(256), 0, stream>>>(
        expand_w, expand_bn, dw_w, dw_bn, id_w, id_bn, merge_bn, proj_w, proj_bn,
        Aexp, ebias, w9f, cstf, Aproj, pscf, pshf);
    k1_expand<<<dim3(HWSZ/64, BB), dim3(256), 0, stream>>>(x, Aexp, ebias, EY);
    k2_dw<<<dim3(24, BB), dim3(128), 0, stream>>>(EY, w9f, cstf, sums);
    k4_proj<<<dim3(HWSZ/64, BB), dim3(256), 0, stream>>>(
        EY, sums, se_red_w, se_red_b, se_exp_w, se_exp_b,
        Aproj, pscf, pshf, x, (float*)d_out);
}